// Round 2
// baseline (333.243 us; speedup 1.0000x reference)
//
#include <hip/hip_runtime.h>

// HungarianCELoss — analytic collapse of the 120-perm matching.
// targets has only 2 distinct rows (fg, bg=1-fg) => cost[b,k,j] has only 2
// distinct values per (b,k); argmin over perms == argmin_k (cost_fg-cost_bg),
// ties -> smallest k (matches lex order of itertools.permutations).
// Per-element identities (x = slot logit, fg = target):
//   sp = softplus(x) = max(x,0) + log(1+exp(-|x|))
//   d  = sp - x ;  sigmoid(x) = exp(-d)
//   A_k = sum sp - x(1-fg) = sum d + x*fg ;  C_k = sum 2*x*fg - x
// Final = [sum_bk A - sum_b C[k*]] / (B*K*N).
// Accumulate per (b): X_k, XF_k, S_k, SF_k (k<5), PX = sum d (all k), Tf.

#define BB 64
#define KK 5
#define NPIX 102400     // 320*320
#define CHUNK_PIX 2048
#define CHUNKS 50       // CHUNKS*CHUNK_PIX == NPIX
#define THREADS 256
#define REC 32          // padded per-b record (22 used)

__global__ __launch_bounds__(1024) void hung_zero(float* __restrict__ ws) {
    ws[blockIdx.x * 1024 + threadIdx.x] = 0.0f;   // grid 2 -> 2048 floats
}

__global__ __launch_bounds__(THREADS, 4) void hung_pass1(
    const float* __restrict__ slot,   // (B,K,N)
    const float* __restrict__ tgt,    // (B,1,N)
    float* __restrict__ ws)           // (B, REC) atomic accumulators
{
    const int b  = blockIdx.y;
    const int cx = blockIdx.x;
    const float* t  = tgt  + (size_t)b * NPIX;
    const float* xb = slot + (size_t)b * KK * NPIX;

    float X[KK]  = {0,0,0,0,0};
    float XF[KK] = {0,0,0,0,0};
    float S[KK]  = {0,0,0,0,0};
    float SF[KK] = {0,0,0,0,0};
    float PX = 0.0f, Tf = 0.0f;

    const int base = cx * CHUNK_PIX + threadIdx.x * 4;
    #pragma unroll
    for (int h = 0; h < 2; ++h) {
        const int pix = base + h * (THREADS * 4);
        const float4 fg4 = *reinterpret_cast<const float4*>(t + pix);
        float4 x4[KK];
        #pragma unroll
        for (int k = 0; k < KK; ++k)
            x4[k] = *reinterpret_cast<const float4*>(xb + (size_t)k * NPIX + pix);

        Tf += (fg4.x + fg4.y) + (fg4.z + fg4.w);
        const float fgv[4] = {fg4.x, fg4.y, fg4.z, fg4.w};
        #pragma unroll
        for (int k = 0; k < KK; ++k) {
            const float xv[4] = {x4[k].x, x4[k].y, x4[k].z, x4[k].w};
            #pragma unroll
            for (int j = 0; j < 4; ++j) {
                const float x  = xv[j];
                const float fg = fgv[j];
                const float e  = __expf(-fabsf(x));     // exp(-|x|)
                const float lg = __logf(1.0f + e);
                const float sp = fmaxf(x, 0.0f) + lg;   // softplus(x)
                const float d  = sp - x;
                const float s  = __expf(-d);            // sigmoid(x)
                PX    += d;
                X[k]  += x;
                XF[k]  = fmaf(x, fg, XF[k]);
                S[k]  += s;
                SF[k]  = fmaf(s, fg, SF[k]);
            }
        }
    }

    float vals[22];
    #pragma unroll
    for (int k = 0; k < KK; ++k) {
        vals[k]      = X[k];
        vals[5 + k]  = XF[k];
        vals[10 + k] = S[k];
        vals[15 + k] = SF[k];
    }
    vals[20] = PX;
    vals[21] = Tf;

    // per-wave butterfly reduce (wave = 64), then lane-0 atomics (f32 HW add)
    #pragma unroll
    for (int j = 0; j < 22; ++j) {
        float v = vals[j];
        #pragma unroll
        for (int off = 32; off > 0; off >>= 1) v += __shfl_down(v, off, 64);
        vals[j] = v;
    }
    if ((threadIdx.x & 63) == 0) {
        float* rec = ws + (size_t)b * REC;
        #pragma unroll
        for (int j = 0; j < 22; ++j) unsafeAtomicAdd(rec + j, vals[j]);
    }
}

__global__ __launch_bounds__(64) void hung_pass2(
    const float* __restrict__ ws, float* __restrict__ out)
{
    const int b = threadIdx.x;          // one image per lane, single wave
    const float* v = ws + (size_t)b * REC;
    const float PX = v[20];
    const float Tf = v[21];
    const float Tb = (float)NPIX - Tf;

    float best = 3.402823466e+38f;
    int   kb   = 0;
    float xfsum = 0.0f;
    #pragma unroll
    for (int k = 0; k < KK; ++k) {
        const float Iv = v[15 + k];          // SF_k = inter_fg
        const float Sv = v[10 + k];
        const float cf = 1.0f - Iv / (Sv + Tf - Iv + 1e-6f);
        const float Ib = Sv - Iv;
        const float cb = 1.0f - Ib / (Sv + Tb - Ib + 1e-6f);
        const float d  = cf - cb;
        if (d < best) { best = d; kb = k; }  // strict < : ties -> smallest k
        xfsum += v[5 + k];
    }
    const float Ck  = 2.0f * v[5 + kb] - v[kb];   // C_{k*} = 2*XF - X
    float res = PX + xfsum - Ck;

    #pragma unroll
    for (int off = 32; off > 0; off >>= 1) res += __shfl_down(res, off, 64);
    if (b == 0)
        out[0] = res * (1.0f / ((float)BB * (float)KK * (float)NPIX));
}

extern "C" void kernel_launch(void* const* d_in, const int* in_sizes, int n_in,
                              void* d_out, int out_size, void* d_ws, size_t ws_size,
                              hipStream_t stream) {
    // setup_inputs order: fg_logits (unused by reference!), slot_logits, target
    const float* slot = (const float*)d_in[1];
    const float* tgt  = (const float*)d_in[2];
    float* out = (float*)d_out;
    float* ws  = (float*)d_ws;

    hung_zero<<<2, 1024, 0, stream>>>(ws);            // zero 2048 floats (>= 64*REC)
    dim3 grid(CHUNKS, BB);
    hung_pass1<<<grid, THREADS, 0, stream>>>(slot, tgt, ws);
    hung_pass2<<<1, 64, 0, stream>>>(ws, out);
}

// Round 3
// 234.235 us; speedup vs baseline: 1.4227x; 1.4227x over previous
//
#include <hip/hip_runtime.h>

// HungarianCELoss — analytic collapse of the 120-perm matching.
// targets has only 2 distinct rows (fg, bg=1-fg) => argmin over perms ==
// argmin_k (cost_fg[k]-cost_bg[k]), ties -> smallest k (lex order of perms).
// Per-element identities (x = slot logit, fg = target):
//   d  = softplus(x) - x = log1p(exp(-|x|)) + max(-x,0);  sigmoid(x) = exp(-d)
//   sum_k A_k = sum d (all k,n) + sum_k XF_k,  C_k = 2*XF_k - X_k
//   answer = [sum_k A_k - C_{k*}] summed over b, / (B*K*N)
// Pass1: block=(chunk,b), 5 waves, wave w owns slot k=w (6 accumulators).
// Pass2: single block reduces 20 chunk-records per b, does argmin + finish.

#define BB 64
#define KK 5
#define NPIX 102400     // 320*320
#define CHUNKS 20
#define CHUNK_PIX 5120  // 20 * 256 ; CHUNKS*CHUNK_PIX == NPIX
#define ITERS 20        // CHUNK_PIX / (64 lanes * 4 floats)
#define THREADS 320     // 5 waves: wave w handles k=w
#define REC 32          // floats per (chunk,b) record; 26 used

__global__ void hung_pass1(const float* __restrict__ slot,   // (B,K,N)
                           const float* __restrict__ tgt,    // (B,1,N)
                           float* __restrict__ ws)           // (CHUNKS,B,REC)
{
    const int b    = blockIdx.y;
    const int cx   = blockIdx.x;
    const int w    = threadIdx.x >> 6;     // wave id == k
    const int lane = threadIdx.x & 63;

    const float* t  = tgt  + (size_t)b * NPIX + cx * CHUNK_PIX;
    const float* xk = slot + ((size_t)b * KK + w) * NPIX + cx * CHUNK_PIX;

    float X = 0.f, XF = 0.f, S = 0.f, SF = 0.f, PX = 0.f, Tf = 0.f;

    #pragma unroll 4
    for (int i = 0; i < ITERS; ++i) {
        const int off = i * 256 + lane * 4;
        const float4 fg4 = *reinterpret_cast<const float4*>(t + off);
        const float4 x4  = *reinterpret_cast<const float4*>(xk + off);
        const float fgv[4] = {fg4.x, fg4.y, fg4.z, fg4.w};
        const float xv[4]  = {x4.x, x4.y, x4.z, x4.w};
        #pragma unroll
        for (int j = 0; j < 4; ++j) {
            const float x  = xv[j];
            const float fg = fgv[j];
            const float e  = __expf(-fabsf(x));     // exp(-|x|)
            const float L  = __logf(1.0f + e);      // log1p(exp(-|x|))
            const float d  = L + fmaxf(-x, 0.0f);   // softplus(x) - x
            const float s  = __expf(-d);            // sigmoid(x)
            PX += d;
            X  += x;
            XF  = fmaf(x, fg, XF);
            S  += s;
            SF  = fmaf(s, fg, SF);
            Tf += fg;
        }
    }

    // per-wave butterfly reduce of 6 values (wave = 64 lanes)
    float v[6] = {X, XF, S, SF, PX, Tf};
    #pragma unroll
    for (int j = 0; j < 6; ++j) {
        float x = v[j];
        #pragma unroll
        for (int off = 32; off > 0; off >>= 1) x += __shfl_down(x, off, 64);
        v[j] = x;
    }
    if (lane == 0) {
        float* rec = ws + (size_t)(cx * BB + b) * REC;
        rec[w]      = v[0];   // X_k
        rec[5 + w]  = v[1];   // XF_k
        rec[10 + w] = v[2];   // S_k
        rec[15 + w] = v[3];   // SF_k
        rec[20 + w] = v[4];   // PX partial (per wave)
        if (w == 0) rec[25] = v[5];   // Tf
    }
}

__global__ __launch_bounds__(256) void hung_pass2(const float* __restrict__ ws,
                                                  float* __restrict__ out)
{
    __shared__ float red[BB][26];
    // column sums over the 20 chunk records (all L2-resident)
    for (int idx = threadIdx.x; idx < BB * 26; idx += 256) {
        const int b = idx / 26, j = idx - b * 26;
        float s = 0.f;
        #pragma unroll 4
        for (int c = 0; c < CHUNKS; ++c)
            s += ws[(size_t)(c * BB + b) * REC + j];
        red[b][j] = s;
    }
    __syncthreads();
    if (threadIdx.x < 64) {                 // wave 0: one image per lane
        const int b = threadIdx.x;
        const float* v = red[b];
        const float Tf = v[25];
        const float Tb = (float)NPIX - Tf;
        float best = 3.402823466e+38f; int kb = 0;
        float xfsum = 0.f, px = 0.f;
        #pragma unroll
        for (int k = 0; k < KK; ++k) {
            const float Sv = v[10 + k], Iv = v[15 + k];     // S_k, inter_fg
            const float cf = 1.f - Iv / (Sv + Tf - Iv + 1e-6f);
            const float Ib = Sv - Iv;
            const float cb = 1.f - Ib / (Sv + Tb - Ib + 1e-6f);
            const float dd = cf - cb;
            if (dd < best) { best = dd; kb = k; }  // strict < : ties -> smallest k
            xfsum += v[5 + k];
            px    += v[20 + k];
        }
        float res = px + xfsum - (2.f * v[5 + kb] - v[kb]);  // - C_{k*}
        #pragma unroll
        for (int off = 32; off > 0; off >>= 1) res += __shfl_down(res, off, 64);
        if (b == 0) out[0] = res * (1.0f / 32768000.0f);   // / (B*K*N)
    }
}

extern "C" void kernel_launch(void* const* d_in, const int* in_sizes, int n_in,
                              void* d_out, int out_size, void* d_ws, size_t ws_size,
                              hipStream_t stream) {
    // setup_inputs order: fg_logits (unused by reference!), slot_logits, target
    const float* slot = (const float*)d_in[1];
    const float* tgt  = (const float*)d_in[2];
    float* out = (float*)d_out;
    float* ws  = (float*)d_ws;

    dim3 grid(CHUNKS, BB);                  // 1280 blocks = 5 per CU, one round
    hung_pass1<<<grid, THREADS, 0, stream>>>(slot, tgt, ws);
    hung_pass2<<<1, 256, 0, stream>>>(ws, out);
}

// Round 4
// 222.689 us; speedup vs baseline: 1.4965x; 1.0518x over previous
//
#include <hip/hip_runtime.h>

// HungarianCELoss — analytic collapse of the 120-perm matching.
// targets has only 2 distinct rows (fg, bg=1-fg) => argmin over perms ==
// argmin_k (cost_fg[k]-cost_bg[k]), ties -> smallest k (lex order of perms).
// Per-element identities (x = slot logit, fg = target):
//   d  = softplus(x) - x = log1p(exp(-|x|)) + max(-x,0);  sigmoid(x) = exp(-d)
//   sum_k A_k = sum d (all k,n) + sum_k XF_k,  C_k = 2*XF_k - X_k
//   answer = [sum_k A_k - C_{k*}] summed over b, / (B*K*N)
//
// R4: pass1 block = one contiguous quarter of a (b,k) plane (100KB slot +
// 100KB target), so consecutive blocks stream consecutive memory (fill-kernel
// pattern) instead of R3's 7680 thin interleaved streams. 6 accumulators.

#define BB 64
#define KK 5
#define NPIX 102400     // 320*320
#define QUARTERS 4
#define SEG 25600       // NPIX / QUARTERS elements (100 KB)
#define ITERS 25        // SEG / (256 threads * 4 floats)
#define THREADS 256
#define REC 8           // floats per (b,k,q) record; 6 used
#define NBLK (BB * KK * QUARTERS)   // 1280

__global__ void hung_pass1(const float* __restrict__ slot,   // (B,K,N)
                           const float* __restrict__ tgt,    // (B,1,N)
                           float* __restrict__ ws)           // (NBLK, REC)
{
    const int bid = blockIdx.x;        // ((b*KK + k)*QUARTERS + q)
    const int q   = bid & (QUARTERS - 1);
    const int bk  = bid >> 2;          // b*KK + k
    const int b   = bk / KK;

    const float* xk = slot + (size_t)bk * NPIX + q * SEG;
    const float* t  = tgt  + (size_t)b  * NPIX + q * SEG;

    float X = 0.f, XF = 0.f, S = 0.f, SF = 0.f, PX = 0.f, Tf = 0.f;

    const int base = threadIdx.x * 4;
    #pragma unroll 5
    for (int i = 0; i < ITERS; ++i) {
        const int off = base + i * (THREADS * 4);
        const float4 fg4 = *reinterpret_cast<const float4*>(t  + off);
        const float4 x4  = *reinterpret_cast<const float4*>(xk + off);
        const float fgv[4] = {fg4.x, fg4.y, fg4.z, fg4.w};
        const float xv[4]  = {x4.x, x4.y, x4.z, x4.w};
        #pragma unroll
        for (int j = 0; j < 4; ++j) {
            const float x  = xv[j];
            const float fg = fgv[j];
            const float e  = __expf(-fabsf(x));     // exp(-|x|)
            const float L  = __logf(1.0f + e);      // log1p(exp(-|x|))
            const float d  = L + fmaxf(-x, 0.0f);   // softplus(x) - x
            const float s  = __expf(-d);            // sigmoid(x)
            PX += d;
            X  += x;
            XF  = fmaf(x, fg, XF);
            S  += s;
            SF  = fmaf(s, fg, SF);
            Tf += fg;
        }
    }

    // block reduce 6 values: per-wave butterfly (wave=64) then LDS combine
    float v[6] = {X, XF, S, SF, PX, Tf};
    #pragma unroll
    for (int j = 0; j < 6; ++j) {
        float x = v[j];
        #pragma unroll
        for (int off = 32; off > 0; off >>= 1) x += __shfl_down(x, off, 64);
        v[j] = x;
    }
    __shared__ float red[THREADS / 64][6];
    const int lane = threadIdx.x & 63;
    const int w    = threadIdx.x >> 6;
    if (lane == 0) {
        #pragma unroll
        for (int j = 0; j < 6; ++j) red[w][j] = v[j];
    }
    __syncthreads();
    if (threadIdx.x < 6) {
        const int j = threadIdx.x;
        ws[(size_t)bid * REC + j] =
            red[0][j] + red[1][j] + red[2][j] + red[3][j];
    }
}

__global__ __launch_bounds__(320) void hung_pass2(const float* __restrict__ ws,
                                                  float* __restrict__ out)
{
    __shared__ float red[BB][KK][6];
    const int t = threadIdx.x;
    if (t < BB * KK) {                 // t == b*KK + k
        float v[6] = {0, 0, 0, 0, 0, 0};
        #pragma unroll
        for (int q = 0; q < QUARTERS; ++q) {
            const float* p = ws + (size_t)(t * QUARTERS + q) * REC;
            #pragma unroll
            for (int j = 0; j < 6; ++j) v[j] += p[j];
        }
        const int b = t / KK, k = t - b * KK;
        #pragma unroll
        for (int j = 0; j < 6; ++j) red[b][k][j] = v[j];
    }
    __syncthreads();
    if (t < BB) {                      // wave 0: one image per lane
        const int b = t;
        const float Tf = red[b][0][5];
        const float Tb = (float)NPIX - Tf;
        float best = 3.402823466e+38f; int kb = 0;
        float xfsum = 0.f, px = 0.f;
        #pragma unroll
        for (int k = 0; k < KK; ++k) {
            const float Sv = red[b][k][2], Iv = red[b][k][3];  // S_k, inter_fg
            const float cf = 1.f - Iv / (Sv + Tf - Iv + 1e-6f);
            const float Ib = Sv - Iv;
            const float cb = 1.f - Ib / (Sv + Tb - Ib + 1e-6f);
            const float dd = cf - cb;
            if (dd < best) { best = dd; kb = k; }  // strict < : ties -> smallest k
            xfsum += red[b][k][1];
            px    += red[b][k][4];
        }
        float res = px + xfsum - (2.f * red[b][kb][1] - red[b][kb][0]);  // - C_{k*}
        #pragma unroll
        for (int off = 32; off > 0; off >>= 1) res += __shfl_down(res, off, 64);
        if (b == 0) out[0] = res * (1.0f / 32768000.0f);   // / (B*K*N)
    }
}

extern "C" void kernel_launch(void* const* d_in, const int* in_sizes, int n_in,
                              void* d_out, int out_size, void* d_ws, size_t ws_size,
                              hipStream_t stream) {
    // setup_inputs order: fg_logits (unused by reference!), slot_logits, target
    const float* slot = (const float*)d_in[1];
    const float* tgt  = (const float*)d_in[2];
    float* out = (float*)d_out;
    float* ws  = (float*)d_ws;

    hung_pass1<<<NBLK, THREADS, 0, stream>>>(slot, tgt, ws);
    hung_pass2<<<1, 320, 0, stream>>>(ws, out);
}